// Round 5
// baseline (266.072 us; speedup 1.0000x reference)
//
#include <hip/hip_runtime.h>
#include <hip/hip_bf16.h>
#include <math.h>

#define BB 4
#define HH 8
#define PP 32
#define NN 32
#define DD 16
#define LL 1024      // PP*NN
#define WINW 10
#define NFF 6
#define PREDL 96
#define SEQL 512
#define EPSF 1.1920928955078125e-07f
#define KROW 24      // shorts per staged key row (48 B, 16B-aligned)
#define KTS 296      // shorts per VT row (288 keys + 8 pad; 592 B, 16B-aligned)
#define PROW 40      // shorts per P row (80 B, 16B-aligned)
#define XROW 20      // floats per xls row (80 B, 16B-aligned)
#define NBLK 1024

typedef __attribute__((ext_vector_type(8))) short bf16x8;
typedef __attribute__((ext_vector_type(4))) float f32x4;

__device__ inline short f2bs(float f) {
    __hip_bfloat16 h = __float2bfloat16(f);
    return *reinterpret_cast<short*>(&h);
}

// Device-scope grid barrier (single-use slot, must be pre-zeroed).
// Safe: grid=1024 blocks, LDS 40448 B -> exactly 4 blocks/CU on 256 CUs,
// all blocks co-resident by capacity. Agent-scope atomics + threadfence
// give cross-XCD visibility of prior global writes.
__device__ __forceinline__ void grid_barrier_wait(unsigned* bar) {
    __syncthreads();
    if (threadIdx.x == 0) {
        __threadfence();
        __hip_atomic_fetch_add(bar, 1u, __ATOMIC_ACQ_REL, __HIP_MEMORY_SCOPE_AGENT);
        while (__hip_atomic_load(bar, __ATOMIC_ACQUIRE, __HIP_MEMORY_SCOPE_AGENT) < NBLK) {}
        __threadfence();
    }
    __syncthreads();
}

// ======= one layer: signed banded attention + RMSNorm + convFFN + RMSNorm ===
// Identical math/layout to the round-3 verified kernel; epilogue guarded by
// if(ch==0) instead of early-return so all threads reach the grid barrier.
__device__ __forceinline__ void layer_body(
    const float* __restrict__ hin, float* __restrict__ hout,
    const float* __restrict__ log_scales, const float* __restrict__ attn_norm,
    const float* __restrict__ up_w, const float* __restrict__ down_w,
    const float* __restrict__ ffn_norm, int layer, int blk, int tid,
    short* hK, short* VT, short (*Pp)[16 * PROW], short (*Pn)[16 * PROW],
    float* xls, float (*comb)[64][8], float (*combl)[2][16])
{
    int bh  = blk >> 5;            // (b*8+h)
    int hh  = bh & 7;
    int p0  = blk & 31;
    int nstage = min(9, (PP - 1) - p0);

    int wid  = tid >> 6;           // wave id
    int qh   = wid >> 1;           // query half (0/1)
    int ch   = wid & 1;            // chunk half (0/1)
    int lane = tid & 63;
    int quad = lane >> 4, n16 = lane & 15;

    // ---- stage keys: fp32 -> bf16, row-major + transposed (256 threads) ----
    {
        const float4* src = (const float4*)(hin + ((size_t)bh * LL + (p0 + 1) * NN) * DD);
        int nf4 = nstage * 128;
        #pragma unroll
        for (int k = 0; k < 5; ++k) {
            int i = tid + k * 256;
            if (i < nf4) {
                int row = i >> 2, j = i & 3;
                float4 v = src[i];
                short s0 = f2bs(v.x), s1 = f2bs(v.y), s2 = f2bs(v.z), s3 = f2bs(v.w);
                unsigned long long u =
                      (unsigned long long)(unsigned short)s0
                    | ((unsigned long long)(unsigned short)s1 << 16)
                    | ((unsigned long long)(unsigned short)s2 << 32)
                    | ((unsigned long long)(unsigned short)s3 << 48);
                *(unsigned long long*)&hK[row * KROW + j * 4] = u;
                int d0 = j * 4;
                VT[(d0 + 0) * KTS + row] = s0;
                VT[(d0 + 1) * KTS + row] = s1;
                VT[(d0 + 2) * KTS + row] = s2;
                VT[(d0 + 3) * KTS + row] = s3;
            }
        }
    }

    // ---- preload Q A-frag and residual (global; overlaps staging) ----
    bf16x8 Aq;
    #pragma unroll
    for (int j = 0; j < 8; ++j) Aq[j] = 0;
    if (quad < 2) {
        const float* qp = hin + ((size_t)bh * LL + p0 * NN + qh * 16 + n16) * DD + quad * 8;
        #pragma unroll
        for (int j = 0; j < 8; ++j) Aq[j] = f2bs(qp[j]);
    }
    float rs[4] = {0.f, 0.f, 0.f, 0.f};
    if (ch == 0) {
        #pragma unroll
        for (int r = 0; r < 4; ++r)
            rs[r] = hin[((size_t)bh * LL + p0 * NN + qh * 16 + quad * 4 + r) * DD + n16];
    }

    float sc  = fminf(fmaxf(__expf(log_scales[layer]), 1.0f), 30.0f) * 0.25f;
    float sc2 = sc * 1.4426950408889634f;   // fold log2(e): exp(x) == exp2(sc2*s)

    __syncthreads();   // staging done

    // ---- chunk loop: ch==0 -> chunks [0,4), ch==1 -> chunks [4,nstage) ----
    f32x4 Op, On;
    Op[0] = Op[1] = Op[2] = Op[3] = 0.f;
    On[0] = On[1] = On[2] = On[3] = 0.f;
    float lpp[4] = {0.f, 0.f, 0.f, 0.f}, lnn[4] = {0.f, 0.f, 0.f, 0.f};
    short* myPp = Pp[wid];
    short* myPn = Pn[wid];

    int c0 = ch ? 4 : 0;
    int c1 = ch ? nstage : min(4, nstage);

    for (int c = c0; c < c1; ++c) {
        int kb = c * 32;
        #pragma unroll
        for (int kt = 0; kt < 2; ++kt) {
            bf16x8 Bk;
            #pragma unroll
            for (int j = 0; j < 8; ++j) Bk[j] = 0;
            if (quad < 2)
                Bk = *(const bf16x8*)&hK[(kb + kt * 16 + n16) * KROW + quad * 8];
            f32x4 z; z[0] = z[1] = z[2] = z[3] = 0.f;
            f32x4 S = __builtin_amdgcn_mfma_f32_16x16x32_bf16(Aq, Bk, z, 0, 0, 0);
            #pragma unroll
            for (int r = 0; r < 4; ++r) {
                float t  = sc2 * S[r];
                float ep = exp2f(t);
                float en = exp2f(-t);
                lpp[r] += ep; lnn[r] += en;
                int pr = quad * 4 + r, pc = kt * 16 + n16;
                myPp[pr * PROW + pc] = f2bs(ep);
                myPn[pr * PROW + pc] = f2bs(en);
            }
        }
        // PV: contiguous b128 frags (same-wave LDS ordering via lgkmcnt)
        bf16x8 Bv = *(const bf16x8*)&VT[n16 * KTS + kb + quad * 8];
        bf16x8 Ap = *(const bf16x8*)&myPp[n16 * PROW + quad * 8];
        bf16x8 An = *(const bf16x8*)&myPn[n16 * PROW + quad * 8];
        Op = __builtin_amdgcn_mfma_f32_16x16x32_bf16(Ap, Bv, Op, 0, 0, 0);
        On = __builtin_amdgcn_mfma_f32_16x16x32_bf16(An, Bv, On, 0, 0, 0);
    }

    // ---- reduce lp/ln over the 16 key-columns (both halves) ----
    #pragma unroll
    for (int r = 0; r < 4; ++r) {
        float a = lpp[r], b = lnn[r];
        a += __shfl_xor(a, 1); a += __shfl_xor(a, 2); a += __shfl_xor(a, 4); a += __shfl_xor(a, 8);
        b += __shfl_xor(b, 1); b += __shfl_xor(b, 2); b += __shfl_xor(b, 4); b += __shfl_xor(b, 8);
        lpp[r] = a; lnn[r] = b;
    }

    // ---- merge ch==1 partials into ch==0 waves ----
    if (ch == 1) {
        *(f32x4*)&comb[qh][lane][0] = Op;
        *(f32x4*)&comb[qh][lane][4] = On;
        if (n16 == 0) {
            #pragma unroll
            for (int r = 0; r < 4; ++r) {
                combl[qh][0][quad * 4 + r] = lpp[r];
                combl[qh][1][quad * 4 + r] = lnn[r];
            }
        }
    }
    __syncthreads();

    if (ch == 0) {
        {
            f32x4 o2 = *(const f32x4*)&comb[qh][lane][0];
            f32x4 n2 = *(const f32x4*)&comb[qh][lane][4];
            #pragma unroll
            for (int r = 0; r < 4; ++r) {
                Op[r] += o2[r];
                On[r] += n2[r];
                lpp[r] += combl[qh][0][quad * 4 + r];
                lnn[r] += combl[qh][1][quad * 4 + r];
            }
        }

        // ---- residual + attn RMSNorm (C-layout), stash rows to xls ----
        #pragma unroll
        for (int r = 0; r < 4; ++r) {
            float lp = lpp[r], ln = lnn[r];
            float rl = (lp > 0.f) ? (1.0f / lp) : 0.f;
            float rn = (ln > 0.f) ? (1.0f / ln) : 0.f;
            float v  = rs[r] + Op[r] * rl - On[r] * rn;
            float ss = v * v;
            ss += __shfl_xor(ss, 1); ss += __shfl_xor(ss, 2);
            ss += __shfl_xor(ss, 4); ss += __shfl_xor(ss, 8);
            float rr = rsqrtf(ss * (1.0f / 16.0f) + EPSF);
            xls[(qh * 16 + quad * 4 + r) * XROW + n16] = v * rr * attn_norm[layer * DD + n16];
        }
        // this wave wrote all 16 of its xls rows -> same-wave LDS ordering, no barrier

        // ---- conv-FFN + residual + RMSNorm: all 64 lanes (16 q x 4 i-groups) ----
        {
            int q = qh * 16 + n16;       // row in xls / output row within block
            int g = quad;                // i-group: i = 4g..4g+3

            const float* uw = up_w + (size_t)(layer * 2 * HH + 2 * hh) * 3;
            float w00 = uw[0], w01 = uw[1], w02 = uw[2];
            float w10 = uw[3], w11 = uw[4], w12 = uw[5];
            const float* dw = down_w + (size_t)(layer * HH + hh) * 2;
            float dc0 = dw[0], dc1 = dw[1];

            float xm2 = g ? xls[q * XROW + 4 * g - 2] : 0.f;
            float xm1 = g ? xls[q * XROW + 4 * g - 1] : 0.f;
            float4 xv = *(const float4*)&xls[q * XROW + 4 * g];
            float xa[6] = {xm2, xm1, xv.x, xv.y, xv.z, xv.w};

            float v4[4], ss = 0.f;
            #pragma unroll
            for (int i = 0; i < 4; ++i) {
                float u0 = w00 * xa[i] + w01 * xa[i + 1] + w02 * xa[i + 2];
                float u1 = w10 * xa[i] + w11 * xa[i + 1] + w12 * xa[i + 2];
                float g0 = 0.5f * u0 * (1.0f + erff(u0 * 0.7071067811865475f));
                float g1 = 0.5f * u1 * (1.0f + erff(u1 * 0.7071067811865475f));
                float vv = xa[i + 2] + dc0 * g0 + dc1 * g1;
                v4[i] = vv; ss += vv * vv;
            }
            ss += __shfl_xor(ss, 16); ss += __shfl_xor(ss, 32);
            float r2 = rsqrtf(ss * (1.0f / 16.0f) + EPSF);

            const float4 fn = *(const float4*)&ffn_norm[layer * DD + 4 * g];
            float* op = hout + ((size_t)bh * LL + p0 * NN + q) * DD + 4 * g;
            float4 o;
            o.x = v4[0] * r2 * fn.x;
            o.y = v4[1] * r2 * fn.y;
            o.z = v4[2] * r2 * fn.z;
            o.w = v4[3] * r2 * fn.w;
            *(float4*)op = o;
        }
    }
}

// Fused: x-copy + layer0 + gridbar + layer1 + gridbar + tail, ONE dispatch.
__global__ __launch_bounds__(256) void fused_kernel(
    const float* __restrict__ tokens, float* __restrict__ hA, float* __restrict__ hB,
    float* __restrict__ out,
    const float* __restrict__ log_scales, const float* __restrict__ attn_norm,
    const float* __restrict__ up_w, const float* __restrict__ down_w,
    const float* __restrict__ ffn_norm,
    const float* __restrict__ mix_w, const float* __restrict__ mix_b,
    const float* __restrict__ fore_w, const float* __restrict__ fore_b,
    const float* __restrict__ x_orig, unsigned* __restrict__ bars)
{
    __shared__ short hK[9 * 32 * KROW];   // 13.8 KB
    __shared__ short VT[16 * KTS];        //  9.5 KB
    __shared__ short Pp[4][16 * PROW];    //  5.0 KB
    __shared__ short Pn[4][16 * PROW];    //  5.0 KB
    __shared__ float xls[32 * XROW];      //  2.5 KB
    __shared__ float comb[2][64][8];      //  4.0 KB
    __shared__ float combl[2][2][16];     //  256 B  => 40448 B -> 4 blocks/CU

    int blk = blockIdx.x;
    int tid = threadIdx.x;

    // ---- x passthrough: 16 float4 per block ----
    if (tid < 16) {
        const float4* x4 = (const float4*)x_orig;
        float4* o4 = (float4*)(out + BB * PREDL * NN);
        o4[blk * 16 + tid] = x4[blk * 16 + tid];
    }

    layer_body(tokens, hA, log_scales, attn_norm, up_w, down_w, ffn_norm, 0,
               blk, tid, hK, VT, Pp, Pn, xls, comb, combl);
    grid_barrier_wait(&bars[0]);
    layer_body(hA, hB, log_scales, attn_norm, up_w, down_w, ffn_norm, 1,
               blk, tid, hK, VT, Pp, Pn, xls, comb, combl);

    // ---- barrier 2: all blocks arrive; only tail blocks (0..3) wait ----
    __syncthreads();
    if (tid == 0) {
        __threadfence();
        __hip_atomic_fetch_add(&bars[1], 1u, __ATOMIC_ACQ_REL, __HIP_MEMORY_SCOPE_AGENT);
    }
    if (blk >= BB) return;
    if (tid == 0) {
        while (__hip_atomic_load(&bars[1], __ATOMIC_ACQUIRE, __HIP_MEMORY_SCOPE_AGENT) < NBLK) {}
        __threadfence();
    }
    __syncthreads();

    // ---- tail: head-mix + forecast projection (coalesced, block b = batch b) ----
    {
        int b   = blk;
        int n   = tid >> 3;           // 0..31
        int d0  = (2 * tid) & 15;     // even d; thread owns (n, d0) and (n, d0+1)

        float mw[8];
        #pragma unroll
        for (int k = 0; k < 8; ++k) mw[k] = mix_w[k];
        float mb = mix_b[0];

        float acc0[NFF] = {0.f, 0.f, 0.f, 0.f, 0.f, 0.f};
        float acc1[NFF] = {0.f, 0.f, 0.f, 0.f, 0.f, 0.f};

        for (int p = 0; p < PP; ++p) {
            float m0 = mb, m1 = mb;
            #pragma unroll
            for (int k = 0; k < 8; ++k) {
                const float* hp = hB + (size_t)(((b * HH + k) * LL) + p * NN + n) * DD + d0;
                float2 hv = *(const float2*)hp;
                m0 += hv.x * mw[k];
                m1 += hv.y * mw[k];
            }
            #pragma unroll
            for (int fi = 0; fi < NFF; ++fi) {
                float w = fore_w[fi * PP + p];
                acc0[fi] += m0 * w;
                acc1[fi] += m1 * w;
            }
        }
        #pragma unroll
        for (int fi = 0; fi < NFF; ++fi) {
            float fb = fore_b[fi];
            out[((b * DD + d0) * NFF + fi) * NN + n]     = acc0[fi] + fb;
            out[((b * DD + d0 + 1) * NFF + fi) * NN + n] = acc1[fi] + fb;
        }
    }
}

// ---------------- host-side input identification by element count ----------------
static int find_by_size(const int* s, int n, int want, int occurrence) {
    int seen = 0;
    for (int i = 0; i < n; ++i)
        if (s[i] == want) { if (seen == occurrence) return i; ++seen; }
    return -1;
}

extern "C" void kernel_launch(void* const* d_in, const int* in_sizes, int n_in,
                              void* d_out, int out_size, void* d_ws, size_t ws_size,
                              hipStream_t stream) {
    int it  = find_by_size(in_sizes, n_in, 524288, 0);
    int ix  = find_by_size(in_sizes, n_in, 65536, 0);
    int ils = find_by_size(in_sizes, n_in, 2, 0);
    int ian = find_by_size(in_sizes, n_in, 32, 0);   // attn_norm_w (1st 32)
    int icu = find_by_size(in_sizes, n_in, 96, 0);
    int icd = find_by_size(in_sizes, n_in, 32, 1);   // conv_down_w (2nd 32)
    int ifn = find_by_size(in_sizes, n_in, 32, 2);   // ffn_norm_w  (3rd 32)
    int imw = find_by_size(in_sizes, n_in, 8, 0);
    int imb = find_by_size(in_sizes, n_in, 1, 0);
    int ifw = find_by_size(in_sizes, n_in, 192, 0);
    int ifb = find_by_size(in_sizes, n_in, 6, 0);
    if (it < 0 || ix < 0 || ils < 0 || ian < 0 || icu < 0 || icd < 0 ||
        ifn < 0 || imw < 0 || imb < 0 || ifw < 0 || ifb < 0) {
        it = 0; ix = 1; ils = 2; ian = 3; icu = 4; icd = 5; ifn = 6;
        imw = 7; imb = 8; ifw = 9; ifb = 10;
    }

    const float* tokens     = (const float*)d_in[it];
    const float* x_orig     = (const float*)d_in[ix];
    const float* log_scales = (const float*)d_in[ils];
    const float* attn_norm  = (const float*)d_in[ian];
    const float* up_w       = (const float*)d_in[icu];
    const float* down_w     = (const float*)d_in[icd];
    const float* ffn_norm   = (const float*)d_in[ifn];
    const float* mix_w      = (const float*)d_in[imw];
    const float* mix_b      = (const float*)d_in[imb];
    const float* fore_w     = (const float*)d_in[ifw];
    const float* fore_b     = (const float*)d_in[ifb];
    float* out = (float*)d_out;

    const size_t NH = (size_t)BB * HH * LL * DD;   // 524288 floats (2 MB)
    float* hA = (float*)d_ws;          // [0, 2 MB)
    float* hB = hA + NH;               // [2, 4 MB)
    unsigned* bars = (unsigned*)(hB + NH);  // [4 MB, +64 B) barrier slots

    // zero the two barrier slots (graph-capturable memset node, in-stream)
    hipMemsetAsync(bars, 0, 64, stream);

    void* args[] = {
        (void*)&tokens, (void*)&hA, (void*)&hB, (void*)&out,
        (void*)&log_scales, (void*)&attn_norm, (void*)&up_w, (void*)&down_w,
        (void*)&ffn_norm, (void*)&mix_w, (void*)&mix_b, (void*)&fore_w,
        (void*)&fore_b, (void*)&x_orig, (void*)&bars
    };
    hipLaunchKernel((void*)fused_kernel, dim3(NBLK), dim3(256), args, 0, stream);
}

// Round 6
// 243.096 us; speedup vs baseline: 1.0945x; 1.0945x over previous
//
#include <hip/hip_runtime.h>
#include <hip/hip_bf16.h>
#include <math.h>

#define BB 4
#define HH 8
#define PP 32
#define NN 32
#define DD 16
#define LL 1024      // PP*NN
#define WINW 10
#define NFF 6
#define PREDL 96
#define SEQL 512
#define EPSF 1.1920928955078125e-07f
#define KROW 24      // shorts per staged key row (48 B, 16B-aligned)
#define KTS 296      // shorts per VT row (288 keys + 8 pad; 592 B, 16B-aligned)
#define PROW 40      // shorts per P row (80 B, 16B-aligned)
#define NBLK 1024

// LDS layout (36096 B total -> 4 blocks/CU guaranteed):
//   [0      , 13824) hK   : keys row-major (9*32 rows x KROW shorts)
//   [13824  , 23296) VT   : keys dim-major (16 x KTS shorts)
//   [23296  , 33536) P    : per-wave P buffers, grouped by ch:
//        ch region (5120 B each): Pp[qh0](1280) Pp[qh1](1280) Pn[qh0](1280) Pn[qh1](1280)
//        comb/combl ALIAS the ch==1 region (each ch1 wave writes only its own
//        Pp/Pn space, which it no longer needs): per qh:
//          combOp = Pp_ch1[qh][0..1024)   combl = Pp_ch1[qh][1024..1152)
//          combOn = Pn_ch1[qh][0..1024)
//   [33536  , 36096) xls  : 32 rows x 20 floats
#define SMEM_BYTES 36096

typedef __attribute__((ext_vector_type(8))) short bf16x8;
typedef __attribute__((ext_vector_type(4))) float f32x4;

__device__ inline short f2bs(float f) {
    __hip_bfloat16 h = __float2bfloat16(f);
    return *reinterpret_cast<short*>(&h);
}

// Two-level grid barrier. bars must be zeroed per launch (memset node).
// 32 groups of 32 blocks; group counters on separate 128 B lines ->
// serialized RMWs per line = 32 (parallel across groups), then 32 on root.
// Last-arriver promotes; only tid==0 of waiting blocks spins on the release
// flag (monotonic generation, one line).
__device__ __forceinline__ void grid_barrier(unsigned* bars, int blk, int tid, bool wait) {
    __syncthreads();
    if (tid == 0) {
        __threadfence();
        unsigned g = (unsigned)blk >> 5;
        unsigned t = __hip_atomic_fetch_add(&bars[g * 32], 1u,
                                            __ATOMIC_ACQ_REL, __HIP_MEMORY_SCOPE_AGENT);
        unsigned gen = t >> 5;
        if ((t & 31u) == 31u) {
            unsigned rt = __hip_atomic_fetch_add(&bars[1024], 1u,
                                                 __ATOMIC_ACQ_REL, __HIP_MEMORY_SCOPE_AGENT);
            if ((rt & 31u) == 31u)
                __hip_atomic_store(&bars[1056], (rt >> 5) + 1u,
                                   __ATOMIC_RELEASE, __HIP_MEMORY_SCOPE_AGENT);
        }
        if (wait) {
            while (__hip_atomic_load(&bars[1056], __ATOMIC_ACQUIRE,
                                     __HIP_MEMORY_SCOPE_AGENT) < gen + 1u)
                __builtin_amdgcn_s_sleep(4);
            __threadfence();
        }
    }
    if (wait) __syncthreads();
}

// ======= one layer: signed banded attention + RMSNorm + convFFN + RMSNorm ===
// Math identical to the round-3 verified kernel; P buffers re-grouped by ch
// so the merge buffers can alias the ch==1 region.
__device__ __forceinline__ void layer_body(
    const float* __restrict__ hin, float* __restrict__ hout,
    const float* __restrict__ log_scales, const float* __restrict__ attn_norm,
    const float* __restrict__ up_w, const float* __restrict__ down_w,
    const float* __restrict__ ffn_norm, int layer, int blk, int tid,
    char* smem)
{
    short* hK   = (short*)smem;
    short* VT   = (short*)(smem + 13824);
    char*  Pb   = smem + 23296;
    float* xls  = (float*)(smem + 33536);

    int bh  = blk >> 5;            // (b*8+h)
    int hh  = bh & 7;
    int p0  = blk & 31;
    int nstage = min(9, (PP - 1) - p0);

    int wid  = tid >> 6;           // wave id
    int qh   = wid >> 1;           // query half (0/1)
    int ch   = wid & 1;            // chunk half (0/1)
    int lane = tid & 63;
    int quad = lane >> 4, n16 = lane & 15;

    short* myPp = (short*)(Pb + ch * 5120 + qh * 1280);
    short* myPn = (short*)(Pb + ch * 5120 + 2560 + qh * 1280);
    f32x4* combOp = (f32x4*)(Pb + 5120 + qh * 1280);          // [lane], 1024 B
    float* combl  = (float*)(Pb + 5120 + qh * 1280 + 1024);   // [2][16], 128 B
    f32x4* combOn = (f32x4*)(Pb + 5120 + 2560 + qh * 1280);   // [lane], 1024 B

    // ---- stage keys: fp32 -> bf16, row-major + transposed (256 threads) ----
    {
        const float4* src = (const float4*)(hin + ((size_t)bh * LL + (p0 + 1) * NN) * DD);
        int nf4 = nstage * 128;
        #pragma unroll
        for (int k = 0; k < 5; ++k) {
            int i = tid + k * 256;
            if (i < nf4) {
                int row = i >> 2, j = i & 3;
                float4 v = src[i];
                short s0 = f2bs(v.x), s1 = f2bs(v.y), s2 = f2bs(v.z), s3 = f2bs(v.w);
                unsigned long long u =
                      (unsigned long long)(unsigned short)s0
                    | ((unsigned long long)(unsigned short)s1 << 16)
                    | ((unsigned long long)(unsigned short)s2 << 32)
                    | ((unsigned long long)(unsigned short)s3 << 48);
                *(unsigned long long*)&hK[row * KROW + j * 4] = u;
                int d0 = j * 4;
                VT[(d0 + 0) * KTS + row] = s0;
                VT[(d0 + 1) * KTS + row] = s1;
                VT[(d0 + 2) * KTS + row] = s2;
                VT[(d0 + 3) * KTS + row] = s3;
            }
        }
    }

    // ---- preload Q A-frag and residual (global; overlaps staging) ----
    bf16x8 Aq;
    #pragma unroll
    for (int j = 0; j < 8; ++j) Aq[j] = 0;
    if (quad < 2) {
        const float* qp = hin + ((size_t)bh * LL + p0 * NN + qh * 16 + n16) * DD + quad * 8;
        #pragma unroll
        for (int j = 0; j < 8; ++j) Aq[j] = f2bs(qp[j]);
    }
    float rs[4] = {0.f, 0.f, 0.f, 0.f};
    if (ch == 0) {
        #pragma unroll
        for (int r = 0; r < 4; ++r)
            rs[r] = hin[((size_t)bh * LL + p0 * NN + qh * 16 + quad * 4 + r) * DD + n16];
    }

    float sc  = fminf(fmaxf(__expf(log_scales[layer]), 1.0f), 30.0f) * 0.25f;
    float sc2 = sc * 1.4426950408889634f;   // fold log2(e): exp(x) == exp2(sc2*s)

    __syncthreads();   // staging done

    // ---- chunk loop: ch==0 -> chunks [0,4), ch==1 -> chunks [4,nstage) ----
    f32x4 Op, On;
    Op[0] = Op[1] = Op[2] = Op[3] = 0.f;
    On[0] = On[1] = On[2] = On[3] = 0.f;
    float lpp[4] = {0.f, 0.f, 0.f, 0.f}, lnn[4] = {0.f, 0.f, 0.f, 0.f};

    int c0 = ch ? 4 : 0;
    int c1 = ch ? nstage : min(4, nstage);

    for (int c = c0; c < c1; ++c) {
        int kb = c * 32;
        #pragma unroll
        for (int kt = 0; kt < 2; ++kt) {
            bf16x8 Bk;
            #pragma unroll
            for (int j = 0; j < 8; ++j) Bk[j] = 0;
            if (quad < 2)
                Bk = *(const bf16x8*)&hK[(kb + kt * 16 + n16) * KROW + quad * 8];
            f32x4 z; z[0] = z[1] = z[2] = z[3] = 0.f;
            f32x4 S = __builtin_amdgcn_mfma_f32_16x16x32_bf16(Aq, Bk, z, 0, 0, 0);
            #pragma unroll
            for (int r = 0; r < 4; ++r) {
                float t  = sc2 * S[r];
                float ep = exp2f(t);
                float en = exp2f(-t);
                lpp[r] += ep; lnn[r] += en;
                int pr = quad * 4 + r, pc = kt * 16 + n16;
                myPp[pr * PROW + pc] = f2bs(ep);
                myPn[pr * PROW + pc] = f2bs(en);
            }
        }
        // PV: contiguous b128 frags (same-wave LDS ordering via lgkmcnt)
        bf16x8 Bv = *(const bf16x8*)&VT[n16 * KTS + kb + quad * 8];
        bf16x8 Ap = *(const bf16x8*)&myPp[n16 * PROW + quad * 8];
        bf16x8 An = *(const bf16x8*)&myPn[n16 * PROW + quad * 8];
        Op = __builtin_amdgcn_mfma_f32_16x16x32_bf16(Ap, Bv, Op, 0, 0, 0);
        On = __builtin_amdgcn_mfma_f32_16x16x32_bf16(An, Bv, On, 0, 0, 0);
    }

    // ---- reduce lp/ln over the 16 key-columns (both halves) ----
    #pragma unroll
    for (int r = 0; r < 4; ++r) {
        float a = lpp[r], b = lnn[r];
        a += __shfl_xor(a, 1); a += __shfl_xor(a, 2); a += __shfl_xor(a, 4); a += __shfl_xor(a, 8);
        b += __shfl_xor(b, 1); b += __shfl_xor(b, 2); b += __shfl_xor(b, 4); b += __shfl_xor(b, 8);
        lpp[r] = a; lnn[r] = b;
    }

    // ---- merge ch==1 partials into ch==0 waves (alias ch1's own P space) ----
    if (ch == 1) {
        combOp[lane] = Op;
        combOn[lane] = On;
        if (n16 == 0) {
            #pragma unroll
            for (int r = 0; r < 4; ++r) {
                combl[quad * 4 + r]      = lpp[r];
                combl[16 + quad * 4 + r] = lnn[r];
            }
        }
    }
    __syncthreads();

    if (ch == 0) {
        {
            f32x4 o2 = combOp[lane];
            f32x4 n2 = combOn[lane];
            #pragma unroll
            for (int r = 0; r < 4; ++r) {
                Op[r] += o2[r];
                On[r] += n2[r];
                lpp[r] += combl[quad * 4 + r];
                lnn[r] += combl[16 + quad * 4 + r];
            }
        }

        // ---- residual + attn RMSNorm (C-layout), stash rows to xls ----
        #pragma unroll
        for (int r = 0; r < 4; ++r) {
            float lp = lpp[r], ln = lnn[r];
            float rl = (lp > 0.f) ? (1.0f / lp) : 0.f;
            float rn = (ln > 0.f) ? (1.0f / ln) : 0.f;
            float v  = rs[r] + Op[r] * rl - On[r] * rn;
            float ss = v * v;
            ss += __shfl_xor(ss, 1); ss += __shfl_xor(ss, 2);
            ss += __shfl_xor(ss, 4); ss += __shfl_xor(ss, 8);
            float rr = rsqrtf(ss * (1.0f / 16.0f) + EPSF);
            xls[(qh * 16 + quad * 4 + r) * 20 + n16] = v * rr * attn_norm[layer * DD + n16];
        }
        // this wave wrote all 16 of its xls rows -> same-wave LDS ordering, no barrier

        // ---- conv-FFN + residual + RMSNorm: all 64 lanes (16 q x 4 i-groups) ----
        {
            int q = qh * 16 + n16;       // row in xls / output row within block
            int g = quad;                // i-group: i = 4g..4g+3

            const float* uw = up_w + (size_t)(layer * 2 * HH + 2 * hh) * 3;
            float w00 = uw[0], w01 = uw[1], w02 = uw[2];
            float w10 = uw[3], w11 = uw[4], w12 = uw[5];
            const float* dw = down_w + (size_t)(layer * HH + hh) * 2;
            float dc0 = dw[0], dc1 = dw[1];

            float xm2 = g ? xls[q * 20 + 4 * g - 2] : 0.f;
            float xm1 = g ? xls[q * 20 + 4 * g - 1] : 0.f;
            float4 xv = *(const float4*)&xls[q * 20 + 4 * g];
            float xa[6] = {xm2, xm1, xv.x, xv.y, xv.z, xv.w};

            float v4[4], ss = 0.f;
            #pragma unroll
            for (int i = 0; i < 4; ++i) {
                float u0 = w00 * xa[i] + w01 * xa[i + 1] + w02 * xa[i + 2];
                float u1 = w10 * xa[i] + w11 * xa[i + 1] + w12 * xa[i + 2];
                float g0 = 0.5f * u0 * (1.0f + erff(u0 * 0.7071067811865475f));
                float g1 = 0.5f * u1 * (1.0f + erff(u1 * 0.7071067811865475f));
                float vv = xa[i + 2] + dc0 * g0 + dc1 * g1;
                v4[i] = vv; ss += vv * vv;
            }
            ss += __shfl_xor(ss, 16); ss += __shfl_xor(ss, 32);
            float r2 = rsqrtf(ss * (1.0f / 16.0f) + EPSF);

            const float4 fn = *(const float4*)&ffn_norm[layer * DD + 4 * g];
            float* op = hout + ((size_t)bh * LL + p0 * NN + q) * DD + 4 * g;
            float4 o;
            o.x = v4[0] * r2 * fn.x;
            o.y = v4[1] * r2 * fn.y;
            o.z = v4[2] * r2 * fn.z;
            o.w = v4[3] * r2 * fn.w;
            *(float4*)op = o;
        }
    }
}

// Fused: x-copy + layer0 + treebar + layer1 + treebar + tail, ONE dispatch.
// LDS 36096 B -> 4 blocks/CU on 256 CUs = full 1024-block co-residency.
__global__ __launch_bounds__(256) void fused_kernel(
    const float* __restrict__ tokens, float* __restrict__ hA, float* __restrict__ hB,
    float* __restrict__ out,
    const float* __restrict__ log_scales, const float* __restrict__ attn_norm,
    const float* __restrict__ up_w, const float* __restrict__ down_w,
    const float* __restrict__ ffn_norm,
    const float* __restrict__ mix_w, const float* __restrict__ mix_b,
    const float* __restrict__ fore_w, const float* __restrict__ fore_b,
    const float* __restrict__ x_orig, unsigned* __restrict__ bars)
{
    __shared__ __align__(16) char smem[SMEM_BYTES];

    int blk = blockIdx.x;
    int tid = threadIdx.x;

    // ---- x passthrough: 16 float4 per block ----
    if (tid < 16) {
        const float4* x4 = (const float4*)x_orig;
        float4* o4 = (float4*)(out + BB * PREDL * NN);
        o4[blk * 16 + tid] = x4[blk * 16 + tid];
    }

    layer_body(tokens, hA, log_scales, attn_norm, up_w, down_w, ffn_norm, 0,
               blk, tid, smem);
    grid_barrier(bars, blk, tid, true);
    layer_body(hA, hB, log_scales, attn_norm, up_w, down_w, ffn_norm, 1,
               blk, tid, smem);

    // ---- barrier 2: all arrive; only tail blocks (0..3) wait ----
    grid_barrier(bars, blk, tid, blk < BB);
    if (blk >= BB) return;

    // ---- tail: head-mix + forecast projection (coalesced, block b = batch b) ----
    {
        int b   = blk;
        int n   = tid >> 3;           // 0..31
        int d0  = (2 * tid) & 15;     // even d; thread owns (n, d0) and (n, d0+1)

        float mw[8];
        #pragma unroll
        for (int k = 0; k < 8; ++k) mw[k] = mix_w[k];
        float mb = mix_b[0];

        float acc0[NFF] = {0.f, 0.f, 0.f, 0.f, 0.f, 0.f};
        float acc1[NFF] = {0.f, 0.f, 0.f, 0.f, 0.f, 0.f};

        for (int p = 0; p < PP; ++p) {
            float m0 = mb, m1 = mb;
            #pragma unroll
            for (int k = 0; k < 8; ++k) {
                const float* hp = hB + (size_t)(((b * HH + k) * LL) + p * NN + n) * DD + d0;
                float2 hv = *(const float2*)hp;
                m0 += hv.x * mw[k];
                m1 += hv.y * mw[k];
            }
            #pragma unroll
            for (int fi = 0; fi < NFF; ++fi) {
                float w = fore_w[fi * PP + p];
                acc0[fi] += m0 * w;
                acc1[fi] += m1 * w;
            }
        }
        #pragma unroll
        for (int fi = 0; fi < NFF; ++fi) {
            float fb = fore_b[fi];
            out[((b * DD + d0) * NFF + fi) * NN + n]     = acc0[fi] + fb;
            out[((b * DD + d0 + 1) * NFF + fi) * NN + n] = acc1[fi] + fb;
        }
    }
}

// ---------------- host-side input identification by element count ----------------
static int find_by_size(const int* s, int n, int want, int occurrence) {
    int seen = 0;
    for (int i = 0; i < n; ++i)
        if (s[i] == want) { if (seen == occurrence) return i; ++seen; }
    return -1;
}

extern "C" void kernel_launch(void* const* d_in, const int* in_sizes, int n_in,
                              void* d_out, int out_size, void* d_ws, size_t ws_size,
                              hipStream_t stream) {
    int it  = find_by_size(in_sizes, n_in, 524288, 0);
    int ix  = find_by_size(in_sizes, n_in, 65536, 0);
    int ils = find_by_size(in_sizes, n_in, 2, 0);
    int ian = find_by_size(in_sizes, n_in, 32, 0);   // attn_norm_w (1st 32)
    int icu = find_by_size(in_sizes, n_in, 96, 0);
    int icd = find_by_size(in_sizes, n_in, 32, 1);   // conv_down_w (2nd 32)
    int ifn = find_by_size(in_sizes, n_in, 32, 2);   // ffn_norm_w  (3rd 32)
    int imw = find_by_size(in_sizes, n_in, 8, 0);
    int imb = find_by_size(in_sizes, n_in, 1, 0);
    int ifw = find_by_size(in_sizes, n_in, 192, 0);
    int ifb = find_by_size(in_sizes, n_in, 6, 0);
    if (it < 0 || ix < 0 || ils < 0 || ian < 0 || icu < 0 || icd < 0 ||
        ifn < 0 || imw < 0 || imb < 0 || ifw < 0 || ifb < 0) {
        it = 0; ix = 1; ils = 2; ian = 3; icu = 4; icd = 5; ifn = 6;
        imw = 7; imb = 8; ifw = 9; ifb = 10;
    }

    const float* tokens     = (const float*)d_in[it];
    const float* x_orig     = (const float*)d_in[ix];
    const float* log_scales = (const float*)d_in[ils];
    const float* attn_norm  = (const float*)d_in[ian];
    const float* up_w       = (const float*)d_in[icu];
    const float* down_w     = (const float*)d_in[icd];
    const float* ffn_norm   = (const float*)d_in[ifn];
    const float* mix_w      = (const float*)d_in[imw];
    const float* mix_b      = (const float*)d_in[imb];
    const float* fore_w     = (const float*)d_in[ifw];
    const float* fore_b     = (const float*)d_in[ifb];
    float* out = (float*)d_out;

    const size_t NH = (size_t)BB * HH * LL * DD;   // 524288 floats (2 MB)
    float* hA = (float*)d_ws;          // [0, 2 MB)
    float* hB = hA + NH;               // [2, 4 MB)
    unsigned* bars = (unsigned*)(hB + NH);  // [4 MB, +4.3 KB) barrier lines

    // reset barrier lines (33 lines x 128 B = 4224 B; graph-capturable node)
    hipMemsetAsync(bars, 0, 4352, stream);

    void* args[] = {
        (void*)&tokens, (void*)&hA, (void*)&hB, (void*)&out,
        (void*)&log_scales, (void*)&attn_norm, (void*)&up_w, (void*)&down_w,
        (void*)&ffn_norm, (void*)&mix_w, (void*)&mix_b, (void*)&fore_w,
        (void*)&fore_b, (void*)&x_orig, (void*)&bars
    };
    hipLaunchKernel((void*)fused_kernel, dim3(NBLK), dim3(256), args, 0, stream);
}

// Round 7
// 171.883 us; speedup vs baseline: 1.5480x; 1.4143x over previous
//
#include <hip/hip_runtime.h>
#include <hip/hip_bf16.h>
#include <math.h>

#define BB 4
#define HH 8
#define PP 32
#define NN 32
#define DD 16
#define LL 1024      // PP*NN
#define WINW 10
#define NFF 6
#define PREDL 96
#define SEQL 512
#define EPSF 1.1920928955078125e-07f
#define KROW 24      // shorts per staged key row (48 B, 16B-aligned)
#define KTS 296      // shorts per VT row (288 keys + 8 pad; 592 B, 16B-aligned)
#define PROW 40      // shorts per P row (80 B, 16B-aligned)
#define XROW 20      // floats per xls row (80 B, 16B-aligned)

typedef __attribute__((ext_vector_type(8))) short bf16x8;
typedef __attribute__((ext_vector_type(4))) float f32x4;

__device__ inline short f2bs(float f) {
    __hip_bfloat16 h = __float2bfloat16(f);
    return *reinterpret_cast<short*>(&h);
}

// ======= one layer: signed banded attention + RMSNorm + convFFN + RMSNorm ===
// Math identical to the round-3 verified kernel (118.6 us, passed); epilogue
// guarded by if(ch==0) (round-5/6 verified variant) so callers can add
// post-layer signaling that all threads reach.
__device__ __forceinline__ void layer_body(
    const float* __restrict__ hin, float* __restrict__ hout,
    const float* __restrict__ log_scales, const float* __restrict__ attn_norm,
    const float* __restrict__ up_w, const float* __restrict__ down_w,
    const float* __restrict__ ffn_norm, int layer, int blk, int tid,
    short* hK, short* VT, short (*Pp)[16 * PROW], short (*Pn)[16 * PROW],
    float* xls, float (*comb)[64][8], float (*combl)[2][16])
{
    int bh  = blk >> 5;            // (b*8+h)
    int hh  = bh & 7;
    int p0  = blk & 31;
    int nstage = min(9, (PP - 1) - p0);

    int wid  = tid >> 6;           // wave id
    int qh   = wid >> 1;           // query half (0/1)
    int ch   = wid & 1;            // chunk half (0/1)
    int lane = tid & 63;
    int quad = lane >> 4, n16 = lane & 15;

    // ---- stage keys: fp32 -> bf16, row-major + transposed (256 threads) ----
    {
        const float4* src = (const float4*)(hin + ((size_t)bh * LL + (p0 + 1) * NN) * DD);
        int nf4 = nstage * 128;
        #pragma unroll
        for (int k = 0; k < 5; ++k) {
            int i = tid + k * 256;
            if (i < nf4) {
                int row = i >> 2, j = i & 3;
                float4 v = src[i];
                short s0 = f2bs(v.x), s1 = f2bs(v.y), s2 = f2bs(v.z), s3 = f2bs(v.w);
                unsigned long long u =
                      (unsigned long long)(unsigned short)s0
                    | ((unsigned long long)(unsigned short)s1 << 16)
                    | ((unsigned long long)(unsigned short)s2 << 32)
                    | ((unsigned long long)(unsigned short)s3 << 48);
                *(unsigned long long*)&hK[row * KROW + j * 4] = u;
                int d0 = j * 4;
                VT[(d0 + 0) * KTS + row] = s0;
                VT[(d0 + 1) * KTS + row] = s1;
                VT[(d0 + 2) * KTS + row] = s2;
                VT[(d0 + 3) * KTS + row] = s3;
            }
        }
    }

    // ---- preload Q A-frag and residual (global; overlaps staging) ----
    bf16x8 Aq;
    #pragma unroll
    for (int j = 0; j < 8; ++j) Aq[j] = 0;
    if (quad < 2) {
        const float* qp = hin + ((size_t)bh * LL + p0 * NN + qh * 16 + n16) * DD + quad * 8;
        #pragma unroll
        for (int j = 0; j < 8; ++j) Aq[j] = f2bs(qp[j]);
    }
    float rs[4] = {0.f, 0.f, 0.f, 0.f};
    if (ch == 0) {
        #pragma unroll
        for (int r = 0; r < 4; ++r)
            rs[r] = hin[((size_t)bh * LL + p0 * NN + qh * 16 + quad * 4 + r) * DD + n16];
    }

    float sc  = fminf(fmaxf(__expf(log_scales[layer]), 1.0f), 30.0f) * 0.25f;
    float sc2 = sc * 1.4426950408889634f;   // fold log2(e): exp(x) == exp2(sc2*s)

    __syncthreads();   // staging done

    // ---- chunk loop: ch==0 -> chunks [0,4), ch==1 -> chunks [4,nstage) ----
    f32x4 Op, On;
    Op[0] = Op[1] = Op[2] = Op[3] = 0.f;
    On[0] = On[1] = On[2] = On[3] = 0.f;
    float lpp[4] = {0.f, 0.f, 0.f, 0.f}, lnn[4] = {0.f, 0.f, 0.f, 0.f};
    short* myPp = Pp[wid];
    short* myPn = Pn[wid];

    int c0 = ch ? 4 : 0;
    int c1 = ch ? nstage : min(4, nstage);

    for (int c = c0; c < c1; ++c) {
        int kb = c * 32;
        #pragma unroll
        for (int kt = 0; kt < 2; ++kt) {
            bf16x8 Bk;
            #pragma unroll
            for (int j = 0; j < 8; ++j) Bk[j] = 0;
            if (quad < 2)
                Bk = *(const bf16x8*)&hK[(kb + kt * 16 + n16) * KROW + quad * 8];
            f32x4 z; z[0] = z[1] = z[2] = z[3] = 0.f;
            f32x4 S = __builtin_amdgcn_mfma_f32_16x16x32_bf16(Aq, Bk, z, 0, 0, 0);
            #pragma unroll
            for (int r = 0; r < 4; ++r) {
                float t  = sc2 * S[r];
                float ep = exp2f(t);
                float en = exp2f(-t);
                lpp[r] += ep; lnn[r] += en;
                int pr = quad * 4 + r, pc = kt * 16 + n16;
                myPp[pr * PROW + pc] = f2bs(ep);
                myPn[pr * PROW + pc] = f2bs(en);
            }
        }
        // PV: contiguous b128 frags (same-wave LDS ordering via lgkmcnt)
        bf16x8 Bv = *(const bf16x8*)&VT[n16 * KTS + kb + quad * 8];
        bf16x8 Ap = *(const bf16x8*)&myPp[n16 * PROW + quad * 8];
        bf16x8 An = *(const bf16x8*)&myPn[n16 * PROW + quad * 8];
        Op = __builtin_amdgcn_mfma_f32_16x16x32_bf16(Ap, Bv, Op, 0, 0, 0);
        On = __builtin_amdgcn_mfma_f32_16x16x32_bf16(An, Bv, On, 0, 0, 0);
    }

    // ---- reduce lp/ln over the 16 key-columns (both halves) ----
    #pragma unroll
    for (int r = 0; r < 4; ++r) {
        float a = lpp[r], b = lnn[r];
        a += __shfl_xor(a, 1); a += __shfl_xor(a, 2); a += __shfl_xor(a, 4); a += __shfl_xor(a, 8);
        b += __shfl_xor(b, 1); b += __shfl_xor(b, 2); b += __shfl_xor(b, 4); b += __shfl_xor(b, 8);
        lpp[r] = a; lnn[r] = b;
    }

    // ---- merge ch==1 partials into ch==0 waves ----
    if (ch == 1) {
        *(f32x4*)&comb[qh][lane][0] = Op;
        *(f32x4*)&comb[qh][lane][4] = On;
        if (n16 == 0) {
            #pragma unroll
            for (int r = 0; r < 4; ++r) {
                combl[qh][0][quad * 4 + r] = lpp[r];
                combl[qh][1][quad * 4 + r] = lnn[r];
            }
        }
    }
    __syncthreads();

    if (ch == 0) {
        {
            f32x4 o2 = *(const f32x4*)&comb[qh][lane][0];
            f32x4 n2 = *(const f32x4*)&comb[qh][lane][4];
            #pragma unroll
            for (int r = 0; r < 4; ++r) {
                Op[r] += o2[r];
                On[r] += n2[r];
                lpp[r] += combl[qh][0][quad * 4 + r];
                lnn[r] += combl[qh][1][quad * 4 + r];
            }
        }

        // ---- residual + attn RMSNorm (C-layout), stash rows to xls ----
        #pragma unroll
        for (int r = 0; r < 4; ++r) {
            float lp = lpp[r], ln = lnn[r];
            float rl = (lp > 0.f) ? (1.0f / lp) : 0.f;
            float rn = (ln > 0.f) ? (1.0f / ln) : 0.f;
            float v  = rs[r] + Op[r] * rl - On[r] * rn;
            float ss = v * v;
            ss += __shfl_xor(ss, 1); ss += __shfl_xor(ss, 2);
            ss += __shfl_xor(ss, 4); ss += __shfl_xor(ss, 8);
            float rr = rsqrtf(ss * (1.0f / 16.0f) + EPSF);
            xls[(qh * 16 + quad * 4 + r) * XROW + n16] = v * rr * attn_norm[layer * DD + n16];
        }
        // this wave wrote all 16 of its xls rows -> same-wave LDS ordering, no barrier

        // ---- conv-FFN + residual + RMSNorm: all 64 lanes (16 q x 4 i-groups) ----
        {
            int q = qh * 16 + n16;       // row in xls / output row within block
            int g = quad;                // i-group: i = 4g..4g+3

            const float* uw = up_w + (size_t)(layer * 2 * HH + 2 * hh) * 3;
            float w00 = uw[0], w01 = uw[1], w02 = uw[2];
            float w10 = uw[3], w11 = uw[4], w12 = uw[5];
            const float* dw = down_w + (size_t)(layer * HH + hh) * 2;
            float dc0 = dw[0], dc1 = dw[1];

            float xm2 = g ? xls[q * XROW + 4 * g - 2] : 0.f;
            float xm1 = g ? xls[q * XROW + 4 * g - 1] : 0.f;
            float4 xv = *(const float4*)&xls[q * XROW + 4 * g];
            float xa[6] = {xm2, xm1, xv.x, xv.y, xv.z, xv.w};

            float v4[4], ss = 0.f;
            #pragma unroll
            for (int i = 0; i < 4; ++i) {
                float u0 = w00 * xa[i] + w01 * xa[i + 1] + w02 * xa[i + 2];
                float u1 = w10 * xa[i] + w11 * xa[i + 1] + w12 * xa[i + 2];
                float g0 = 0.5f * u0 * (1.0f + erff(u0 * 0.7071067811865475f));
                float g1 = 0.5f * u1 * (1.0f + erff(u1 * 0.7071067811865475f));
                float vv = xa[i + 2] + dc0 * g0 + dc1 * g1;
                v4[i] = vv; ss += vv * vv;
            }
            ss += __shfl_xor(ss, 16); ss += __shfl_xor(ss, 32);
            float r2 = rsqrtf(ss * (1.0f / 16.0f) + EPSF);

            const float4 fn = *(const float4*)&ffn_norm[layer * DD + 4 * g];
            float* op = hout + ((size_t)bh * LL + p0 * NN + q) * DD + 4 * g;
            float4 o;
            o.x = v4[0] * r2 * fn.x;
            o.y = v4[1] * r2 * fn.y;
            o.z = v4[2] * r2 * fn.z;
            o.w = v4[3] * r2 * fn.w;
            *(float4*)op = o;
        }
    }
}

// ======= dispatch 1: layer 0 + x-passthrough + flag zeroing ==================
__global__ __launch_bounds__(256) void layer0_kernel(
    const float* __restrict__ tokens, float* __restrict__ hA,
    const float* __restrict__ log_scales, const float* __restrict__ attn_norm,
    const float* __restrict__ up_w, const float* __restrict__ down_w,
    const float* __restrict__ ffn_norm,
    const float* __restrict__ x_orig, float* __restrict__ xdst,
    unsigned* __restrict__ bars)
{
    __shared__ short hK[9 * 32 * KROW];
    __shared__ short VT[16 * KTS];
    __shared__ short Pp[4][16 * PROW];
    __shared__ short Pn[4][16 * PROW];
    __shared__ float xls[32 * XROW];
    __shared__ float comb[2][64][8];
    __shared__ float combl[2][2][16];

    int blk = blockIdx.x;
    int tid = threadIdx.x;

    // zero completion counters/flags for the next dispatch (1280 uints)
    if (blk == 0) {
        for (int i = tid; i < 1280; i += 256) bars[i] = 0;
    }

    // x passthrough: 16 float4 per block
    if (tid < 16) {
        const float4* x4 = (const float4*)x_orig;
        float4* o4 = (float4*)xdst;
        o4[blk * 16 + tid] = x4[blk * 16 + tid];
    }

    layer_body(tokens, hA, log_scales, attn_norm, up_w, down_w, ffn_norm, 0,
               blk, tid, hK, VT, Pp, Pn, xls, comb, combl);
}

// ======= dispatch 2: layer 1 + completion flags + tail on 4 blocks ==========
// Producer-consumer, NOT a grid barrier: every block signals, only the 4
// p0==31 blocks (zero attention work) wait, then compute the tail for their
// batch. Spinners wait only on producers; producers never wait -> safe at any
// occupancy / dispatch order.
__global__ __launch_bounds__(256) void layer1_tail_kernel(
    const float* __restrict__ hA, float* __restrict__ hB,
    const float* __restrict__ log_scales, const float* __restrict__ attn_norm,
    const float* __restrict__ up_w, const float* __restrict__ down_w,
    const float* __restrict__ ffn_norm,
    const float* __restrict__ mix_w, const float* __restrict__ mix_b,
    const float* __restrict__ fore_w, const float* __restrict__ fore_b,
    float* __restrict__ out, unsigned* __restrict__ bars)
{
    __shared__ short hK[9 * 32 * KROW];
    __shared__ short VT[16 * KTS];
    __shared__ short Pp[4][16 * PROW];
    __shared__ short Pn[4][16 * PROW];
    __shared__ float xls[32 * XROW];
    __shared__ float comb[2][64][8];
    __shared__ float combl[2][2][16];

    int blk = blockIdx.x;
    int tid = threadIdx.x;
    int bh  = blk >> 5;
    int b   = blk >> 8;

    layer_body(hA, hB, log_scales, attn_norm, up_w, down_w, ffn_norm, 1,
               blk, tid, hK, VT, Pp, Pn, xls, comb, combl);

    // ---- signal completion (two-level counter tree; verified fence pattern) ----
    __syncthreads();
    if (tid == 0) {
        __threadfence();
        unsigned t = __hip_atomic_fetch_add(&bars[bh * 32], 1u,
                                            __ATOMIC_ACQ_REL, __HIP_MEMORY_SCOPE_AGENT);
        if (t == 31u) {   // all 32 patches of this (b,h) done
            unsigned rb = __hip_atomic_fetch_add(&bars[1024 + b * 32], 1u,
                                                 __ATOMIC_ACQ_REL, __HIP_MEMORY_SCOPE_AGENT);
            if (rb == 7u) // all 8 heads of this batch done
                __hip_atomic_store(&bars[1152 + b * 32], 1u,
                                   __ATOMIC_RELEASE, __HIP_MEMORY_SCOPE_AGENT);
        }
    }

    if ((blk & 255) != 255) return;   // only the 4 p0==31 blocks run the tail

    if (tid == 0) {
        while (__hip_atomic_load(&bars[1152 + b * 32], __ATOMIC_ACQUIRE,
                                 __HIP_MEMORY_SCOPE_AGENT) == 0u)
            __builtin_amdgcn_s_sleep(8);
        __threadfence();
    }
    __syncthreads();

    // ---- tail: head-mix + forecast projection (coalesced; batch b) ----
    {
        int n   = tid >> 3;           // 0..31
        int d0  = (2 * tid) & 15;     // even d; thread owns (n, d0) and (n, d0+1)

        float mw[8];
        #pragma unroll
        for (int k = 0; k < 8; ++k) mw[k] = mix_w[k];
        float mb = mix_b[0];

        float acc0[NFF] = {0.f, 0.f, 0.f, 0.f, 0.f, 0.f};
        float acc1[NFF] = {0.f, 0.f, 0.f, 0.f, 0.f, 0.f};

        for (int p = 0; p < PP; ++p) {
            float m0 = mb, m1 = mb;
            #pragma unroll
            for (int k = 0; k < 8; ++k) {
                const float* hp = hB + (size_t)(((b * HH + k) * LL) + p * NN + n) * DD + d0;
                float2 hv = *(const float2*)hp;
                m0 += hv.x * mw[k];
                m1 += hv.y * mw[k];
            }
            #pragma unroll
            for (int fi = 0; fi < NFF; ++fi) {
                float w = fore_w[fi * PP + p];
                acc0[fi] += m0 * w;
                acc1[fi] += m1 * w;
            }
        }
        #pragma unroll
        for (int fi = 0; fi < NFF; ++fi) {
            float fb = fore_b[fi];
            out[((b * DD + d0) * NFF + fi) * NN + n]     = acc0[fi] + fb;
            out[((b * DD + d0 + 1) * NFF + fi) * NN + n] = acc1[fi] + fb;
        }
    }
}

// ---------------- host-side input identification by element count ----------------
static int find_by_size(const int* s, int n, int want, int occurrence) {
    int seen = 0;
    for (int i = 0; i < n; ++i)
        if (s[i] == want) { if (seen == occurrence) return i; ++seen; }
    return -1;
}

extern "C" void kernel_launch(void* const* d_in, const int* in_sizes, int n_in,
                              void* d_out, int out_size, void* d_ws, size_t ws_size,
                              hipStream_t stream) {
    int it  = find_by_size(in_sizes, n_in, 524288, 0);
    int ix  = find_by_size(in_sizes, n_in, 65536, 0);
    int ils = find_by_size(in_sizes, n_in, 2, 0);
    int ian = find_by_size(in_sizes, n_in, 32, 0);   // attn_norm_w (1st 32)
    int icu = find_by_size(in_sizes, n_in, 96, 0);
    int icd = find_by_size(in_sizes, n_in, 32, 1);   // conv_down_w (2nd 32)
    int ifn = find_by_size(in_sizes, n_in, 32, 2);   // ffn_norm_w  (3rd 32)
    int imw = find_by_size(in_sizes, n_in, 8, 0);
    int imb = find_by_size(in_sizes, n_in, 1, 0);
    int ifw = find_by_size(in_sizes, n_in, 192, 0);
    int ifb = find_by_size(in_sizes, n_in, 6, 0);
    if (it < 0 || ix < 0 || ils < 0 || ian < 0 || icu < 0 || icd < 0 ||
        ifn < 0 || imw < 0 || imb < 0 || ifw < 0 || ifb < 0) {
        it = 0; ix = 1; ils = 2; ian = 3; icu = 4; icd = 5; ifn = 6;
        imw = 7; imb = 8; ifw = 9; ifb = 10;
    }

    const float* tokens     = (const float*)d_in[it];
    const float* x_orig     = (const float*)d_in[ix];
    const float* log_scales = (const float*)d_in[ils];
    const float* attn_norm  = (const float*)d_in[ian];
    const float* up_w       = (const float*)d_in[icu];
    const float* down_w     = (const float*)d_in[icd];
    const float* ffn_norm   = (const float*)d_in[ifn];
    const float* mix_w      = (const float*)d_in[imw];
    const float* mix_b      = (const float*)d_in[imb];
    const float* fore_w     = (const float*)d_in[ifw];
    const float* fore_b     = (const float*)d_in[ifb];
    float* out = (float*)d_out;

    const size_t NH = (size_t)BB * HH * LL * DD;   // 524288 floats (2 MB)
    float* hA = (float*)d_ws;               // [0, 2 MB)
    float* hB = hA + NH;                    // [2, 4 MB)
    unsigned* bars = (unsigned*)(hB + NH);  // [4 MB, +5120 B) counters/flags

    layer0_kernel<<<1024, 256, 0, stream>>>(tokens, hA, log_scales, attn_norm,
                                            up_w, down_w, ffn_norm,
                                            x_orig, out + BB * PREDL * NN, bars);
    layer1_tail_kernel<<<1024, 256, 0, stream>>>(hA, hB, log_scales, attn_norm,
                                                 up_w, down_w, ffn_norm,
                                                 mix_w, mix_b, fore_w, fore_b,
                                                 out, bars);
}

// Round 8
// 118.515 us; speedup vs baseline: 2.2450x; 1.4503x over previous
//
#include <hip/hip_runtime.h>
#include <hip/hip_bf16.h>
#include <math.h>

#define BB 4
#define HH 8
#define PP 32
#define NN 32
#define DD 16
#define LL 1024      // PP*NN
#define WINW 10
#define NFF 6
#define PREDL 96
#define SEQL 512
#define EPSF 1.1920928955078125e-07f
#define KROW 24      // shorts per staged key row (48 B, 16B-aligned)
#define KTS 296      // shorts per VT row (288 keys + 8 pad; 592 B, 16B-aligned)
#define PROW 40      // shorts per P row (80 B, 16B-aligned)
#define XROW 20      // floats per xls row (80 B, 16B-aligned)

typedef __attribute__((ext_vector_type(8))) short bf16x8;
typedef __attribute__((ext_vector_type(4))) float f32x4;

// packed bf16 pair convert (RNE), 1 VALU op for 2 values
__device__ __forceinline__ unsigned cvtpk(float a, float b) {
    unsigned r;
    asm("v_cvt_pk_bf16_f32 %0, %1, %2" : "=v"(r) : "v"(a), "v"(b));
    return r;
}
__device__ __forceinline__ unsigned long long pk64(unsigned lo, unsigned hi) {
    return (unsigned long long)lo | ((unsigned long long)hi << 32);
}

// ======= MFMA fused layer: signed banded attention + RMSNorm + convFFN + RMSNorm ===
// Grid: 1024 blocks x 256 (4 waves per (b,h,patch)); wave = (qh, ch).
// SWAPPED QK^T: S' = mfma(A=K, B=Q) so S' rows are KEYS. Lane (quad,n16) holds
// P[key kt*16+quad*4+r][query n16] -> P staged to LDS with ONE ds_write_b64 per
// tile per P-type (vs 32 ds_write_b16/chunk), packed by v_cvt_pk_bf16_f32.
// PV read side (P[query row][key cols] as b128) is unchanged.
__global__ __launch_bounds__(256) void layer_kernel(
    const float* __restrict__ hin, float* __restrict__ hout,
    const float* __restrict__ log_scales, const float* __restrict__ attn_norm,
    const float* __restrict__ up_w, const float* __restrict__ down_w,
    const float* __restrict__ ffn_norm, int layer,
    const float* __restrict__ xsrc, float* __restrict__ xdst)
{
    __shared__ short hK[9 * 32 * KROW];   // 13.8 KB keys row-major
    __shared__ short VT[16 * KTS];        //  9.5 KB keys dim-major (transposed)
    __shared__ short Pp[4][16 * PROW];    //  5.0 KB (per-wave)
    __shared__ short Pn[4][16 * PROW];    //  5.0 KB
    __shared__ float xls[32 * XROW];      //  2.5 KB
    __shared__ float comb[2][64][8];      //  4.0 KB partial Op/On exchange
    __shared__ float combl[2][2][16];     //  256 B partial lp/ln exchange

    int blk = blockIdx.x;
    int bh  = blk >> 5;            // (b*8+h)
    int hh  = bh & 7;
    int p0  = blk & 31;
    int nstage = min(9, (PP - 1) - p0);

    int tid  = threadIdx.x;
    int wid  = tid >> 6;           // wave id
    int qh   = wid >> 1;           // query half (0/1)
    int ch   = wid & 1;            // chunk half (0/1)
    int lane = tid & 63;
    int quad = lane >> 4, n16 = lane & 15;

    // ---- x passthrough (layer 0 only): 16 float4 per block ----
    if (xsrc && tid < 16) {
        const float4* x4 = (const float4*)xsrc;
        float4* o4 = (float4*)xdst;
        o4[blk * 16 + tid] = x4[blk * 16 + tid];
    }

    // ---- stage keys: fp32 -> bf16 (cvt_pk), row-major + transposed ----
    {
        const float4* src = (const float4*)(hin + ((size_t)bh * LL + (p0 + 1) * NN) * DD);
        int nf4 = nstage * 128;
        #pragma unroll
        for (int k = 0; k < 5; ++k) {
            int i = tid + k * 256;
            if (i < nf4) {
                int row = i >> 2, j = i & 3;
                float4 v = src[i];
                unsigned pk0 = cvtpk(v.x, v.y);
                unsigned pk1 = cvtpk(v.z, v.w);
                *(unsigned long long*)&hK[row * KROW + j * 4] = pk64(pk0, pk1);
                int d0 = j * 4;
                VT[(d0 + 0) * KTS + row] = (short)(pk0 & 0xffff);
                VT[(d0 + 1) * KTS + row] = (short)(pk0 >> 16);
                VT[(d0 + 2) * KTS + row] = (short)(pk1 & 0xffff);
                VT[(d0 + 3) * KTS + row] = (short)(pk1 >> 16);
            }
        }
    }

    // ---- preload Q B-frag and residual (global; overlaps staging) ----
    bf16x8 Aq;
    #pragma unroll
    for (int j = 0; j < 8; ++j) Aq[j] = 0;
    if (quad < 2) {
        const float4* qp4 = (const float4*)(hin +
            ((size_t)bh * LL + p0 * NN + qh * 16 + n16) * DD + quad * 8);
        float4 a = qp4[0], b = qp4[1];
        union { bf16x8 v; unsigned u[4]; } uu;
        uu.u[0] = cvtpk(a.x, a.y);
        uu.u[1] = cvtpk(a.z, a.w);
        uu.u[2] = cvtpk(b.x, b.y);
        uu.u[3] = cvtpk(b.z, b.w);
        Aq = uu.v;
    }
    float rs[4] = {0.f, 0.f, 0.f, 0.f};
    if (ch == 0) {
        #pragma unroll
        for (int r = 0; r < 4; ++r)
            rs[r] = hin[((size_t)bh * LL + p0 * NN + qh * 16 + quad * 4 + r) * DD + n16];
    }

    float sc  = fminf(fmaxf(__expf(log_scales[layer]), 1.0f), 30.0f) * 0.25f;
    float sc2 = sc * 1.4426950408889634f;   // fold log2(e): exp(x) == exp2(sc2*s)

    __syncthreads();   // staging done

    // ---- chunk loop: ch==0 -> chunks [0,4), ch==1 -> chunks [4,nstage) ----
    f32x4 Op, On;
    Op[0] = Op[1] = Op[2] = Op[3] = 0.f;
    On[0] = On[1] = On[2] = On[3] = 0.f;
    float lpp = 0.f, lnn = 0.f;    // per-lane partial for query n16 (keys quad*4+r slices)
    short* myPp = Pp[wid];
    short* myPn = Pn[wid];

    int c0 = ch ? 4 : 0;
    int c1 = ch ? nstage : min(4, nstage);

    for (int c = c0; c < c1; ++c) {
        int kb = c * 32;
        #pragma unroll
        for (int kt = 0; kt < 2; ++kt) {
            bf16x8 Bk;   // K fragment (A operand after swap)
            #pragma unroll
            for (int j = 0; j < 8; ++j) Bk[j] = 0;
            if (quad < 2)
                Bk = *(const bf16x8*)&hK[(kb + kt * 16 + n16) * KROW + quad * 8];
            f32x4 z; z[0] = z[1] = z[2] = z[3] = 0.f;
            // SWAPPED: S'[key kt*16+quad*4+r][query n16]
            f32x4 S = __builtin_amdgcn_mfma_f32_16x16x32_bf16(Bk, Aq, z, 0, 0, 0);
            float ep[4], en[4];
            #pragma unroll
            for (int r = 0; r < 4; ++r) {
                float t = sc2 * S[r];
                ep[r] = exp2f(t);
                en[r] = exp2f(-t);
                lpp += ep[r]; lnn += en[r];
            }
            // one b64 write per P-type: P[query n16][keys kt*16+quad*4 .. +3]
            *(unsigned long long*)&myPp[n16 * PROW + kt * 16 + quad * 4] =
                pk64(cvtpk(ep[0], ep[1]), cvtpk(ep[2], ep[3]));
            *(unsigned long long*)&myPn[n16 * PROW + kt * 16 + quad * 4] =
                pk64(cvtpk(en[0], en[1]), cvtpk(en[2], en[3]));
        }
        // PV: contiguous b128 frags (same-wave LDS ordering via lgkmcnt)
        bf16x8 Bv = *(const bf16x8*)&VT[n16 * KTS + kb + quad * 8];
        bf16x8 Ap = *(const bf16x8*)&myPp[n16 * PROW + quad * 8];
        bf16x8 An = *(const bf16x8*)&myPn[n16 * PROW + quad * 8];
        Op = __builtin_amdgcn_mfma_f32_16x16x32_bf16(Ap, Bv, Op, 0, 0, 0);
        On = __builtin_amdgcn_mfma_f32_16x16x32_bf16(An, Bv, On, 0, 0, 0);
    }

    // ---- reduce lp/ln over quads (each lane then has full sum for query n16) ----
    lpp += __shfl_xor(lpp, 16); lpp += __shfl_xor(lpp, 32);
    lnn += __shfl_xor(lnn, 16); lnn += __shfl_xor(lnn, 32);

    // ---- merge ch==1 partials into ch==0 waves ----
    if (ch == 1) {
        *(f32x4*)&comb[qh][lane][0] = Op;
        *(f32x4*)&comb[qh][lane][4] = On;
        if (lane < 16) {
            combl[qh][0][lane] = lpp;
            combl[qh][1][lane] = lnn;
        }
    }
    __syncthreads();
    if (ch == 1) return;   // no barriers past this point

    {
        f32x4 o2 = *(const f32x4*)&comb[qh][lane][0];
        f32x4 n2 = *(const f32x4*)&comb[qh][lane][4];
        #pragma unroll
        for (int r = 0; r < 4; ++r) { Op[r] += o2[r]; On[r] += n2[r]; }
        lpp += combl[qh][0][n16];
        lnn += combl[qh][1][n16];
    }

    // redistribute lp/ln to the O-fragment's row indexing (query quad*4+r)
    float lpr[4], lnr[4];
    #pragma unroll
    for (int r = 0; r < 4; ++r) {
        lpr[r] = __shfl(lpp, quad * 4 + r);
        lnr[r] = __shfl(lnn, quad * 4 + r);
    }

    // ---- residual + attn RMSNorm (C-layout), stash rows to xls ----
    #pragma unroll
    for (int r = 0; r < 4; ++r) {
        float lp = lpr[r], ln = lnr[r];
        float rl = (lp > 0.f) ? (1.0f / lp) : 0.f;
        float rn = (ln > 0.f) ? (1.0f / ln) : 0.f;
        float v  = rs[r] + Op[r] * rl - On[r] * rn;
        float ss = v * v;
        ss += __shfl_xor(ss, 1); ss += __shfl_xor(ss, 2);
        ss += __shfl_xor(ss, 4); ss += __shfl_xor(ss, 8);
        float rr = rsqrtf(ss * (1.0f / 16.0f) + EPSF);
        xls[(qh * 16 + quad * 4 + r) * XROW + n16] = v * rr * attn_norm[layer * DD + n16];
    }
    // this wave wrote all 16 of its xls rows -> same-wave LDS ordering, no barrier

    // ---- conv-FFN + residual + RMSNorm: all 64 lanes (16 q x 4 i-groups) ----
    {
        int q = qh * 16 + n16;       // row in xls / output row within block
        int g = quad;                // i-group: i = 4g..4g+3

        const float* uw = up_w + (size_t)(layer * 2 * HH + 2 * hh) * 3;
        float w00 = uw[0], w01 = uw[1], w02 = uw[2];
        float w10 = uw[3], w11 = uw[4], w12 = uw[5];
        const float* dw = down_w + (size_t)(layer * HH + hh) * 2;
        float dc0 = dw[0], dc1 = dw[1];

        float xm2 = g ? xls[q * XROW + 4 * g - 2] : 0.f;
        float xm1 = g ? xls[q * XROW + 4 * g - 1] : 0.f;
        float4 xv = *(const float4*)&xls[q * XROW + 4 * g];
        float xa[6] = {xm2, xm1, xv.x, xv.y, xv.z, xv.w};

        float v4[4], ss = 0.f;
        #pragma unroll
        for (int i = 0; i < 4; ++i) {
            float u0 = w00 * xa[i] + w01 * xa[i + 1] + w02 * xa[i + 2];
            float u1 = w10 * xa[i] + w11 * xa[i + 1] + w12 * xa[i + 2];
            float g0 = 0.5f * u0 * (1.0f + erff(u0 * 0.7071067811865475f));
            float g1 = 0.5f * u1 * (1.0f + erff(u1 * 0.7071067811865475f));
            float vv = xa[i + 2] + dc0 * g0 + dc1 * g1;
            v4[i] = vv; ss += vv * vv;
        }
        ss += __shfl_xor(ss, 16); ss += __shfl_xor(ss, 32);
        float r2 = rsqrtf(ss * (1.0f / 16.0f) + EPSF);

        const float4 fn = *(const float4*)&ffn_norm[layer * DD + 4 * g];
        float* op = hout + ((size_t)bh * LL + p0 * NN + q) * DD + 4 * g;
        float4 o;
        o.x = v4[0] * r2 * fn.x;
        o.y = v4[1] * r2 * fn.y;
        o.z = v4[2] * r2 * fn.z;
        o.w = v4[3] * r2 * fn.w;
        *(float4*)op = o;
    }
}

// ---------------- tail: head-mix + forecast projection (coalesced, 4 blocks) ----
__global__ __launch_bounds__(256) void tail_kernel(
    const float* __restrict__ h, const float* __restrict__ mw_,
    const float* __restrict__ mb_, const float* __restrict__ fw_,
    const float* __restrict__ fb_, float* __restrict__ out)
{
    int b   = blockIdx.x;
    int tid = threadIdx.x;
    int n   = tid >> 3;           // 0..31
    int d0  = (2 * tid) & 15;     // even d; thread owns (n, d0) and (n, d0+1)

    float mw[8];
    #pragma unroll
    for (int k = 0; k < 8; ++k) mw[k] = mw_[k];
    float mb = mb_[0];

    float acc0[NFF] = {0.f, 0.f, 0.f, 0.f, 0.f, 0.f};
    float acc1[NFF] = {0.f, 0.f, 0.f, 0.f, 0.f, 0.f};

    for (int p = 0; p < PP; ++p) {
        float m0 = mb, m1 = mb;
        #pragma unroll
        for (int k = 0; k < 8; ++k) {
            const float* hp = h + (size_t)(((b * HH + k) * LL) + p * NN + n) * DD + d0;
            float2 hv = *(const float2*)hp;
            m0 += hv.x * mw[k];
            m1 += hv.y * mw[k];
        }
        #pragma unroll
        for (int fi = 0; fi < NFF; ++fi) {
            float w = fw_[fi * PP + p];
            acc0[fi] += m0 * w;
            acc1[fi] += m1 * w;
        }
    }
    #pragma unroll
    for (int fi = 0; fi < NFF; ++fi) {
        float fb = fb_[fi];
        out[((b * DD + d0) * NFF + fi) * NN + n]     = acc0[fi] + fb;
        out[((b * DD + d0 + 1) * NFF + fi) * NN + n] = acc1[fi] + fb;
    }
}

// ---------------- host-side input identification by element count ----------------
static int find_by_size(const int* s, int n, int want, int occurrence) {
    int seen = 0;
    for (int i = 0; i < n; ++i)
        if (s[i] == want) { if (seen == occurrence) return i; ++seen; }
    return -1;
}

extern "C" void kernel_launch(void* const* d_in, const int* in_sizes, int n_in,
                              void* d_out, int out_size, void* d_ws, size_t ws_size,
                              hipStream_t stream) {
    int it  = find_by_size(in_sizes, n_in, 524288, 0);
    int ix  = find_by_size(in_sizes, n_in, 65536, 0);
    int ils = find_by_size(in_sizes, n_in, 2, 0);
    int ian = find_by_size(in_sizes, n_in, 32, 0);   // attn_norm_w (1st 32)
    int icu = find_by_size(in_sizes, n_in, 96, 0);
    int icd = find_by_size(in_sizes, n_in, 32, 1);   // conv_down_w (2nd 32)
    int ifn = find_by_size(in_sizes, n_in, 32, 2);   // ffn_norm_w  (3rd 32)
    int imw = find_by_size(in_sizes, n_in, 8, 0);
    int imb = find_by_size(in_sizes, n_in, 1, 0);
    int ifw = find_by_size(in_sizes, n_in, 192, 0);
    int ifb = find_by_size(in_sizes, n_in, 6, 0);
    if (it < 0 || ix < 0 || ils < 0 || ian < 0 || icu < 0 || icd < 0 ||
        ifn < 0 || imw < 0 || imb < 0 || ifw < 0 || ifb < 0) {
        it = 0; ix = 1; ils = 2; ian = 3; icu = 4; icd = 5; ifn = 6;
        imw = 7; imb = 8; ifw = 9; ifb = 10;
    }

    const float* tokens     = (const float*)d_in[it];
    const float* x_orig     = (const float*)d_in[ix];
    const float* log_scales = (const float*)d_in[ils];
    const float* attn_norm  = (const float*)d_in[ian];
    const float* up_w       = (const float*)d_in[icu];
    const float* down_w     = (const float*)d_in[icd];
    const float* ffn_norm   = (const float*)d_in[ifn];
    const float* mix_w      = (const float*)d_in[imw];
    const float* mix_b      = (const float*)d_in[imb];
    const float* fore_w     = (const float*)d_in[ifw];
    const float* fore_b     = (const float*)d_in[ifb];
    float* out = (float*)d_out;

    const size_t NH = (size_t)BB * HH * LL * DD;
    float* hA = (float*)d_ws;        // [0, 2 MB)
    float* hB = hA + NH;             // [2, 4 MB)

    layer_kernel<<<1024, 256, 0, stream>>>(tokens, hA, log_scales, attn_norm,
                                           up_w, down_w, ffn_norm, 0,
                                           x_orig, out + BB * PREDL * NN);
    layer_kernel<<<1024, 256, 0, stream>>>(hA, hB, log_scales, attn_norm,
                                           up_w, down_w, ffn_norm, 1,
                                           (const float*)nullptr, (float*)nullptr);
    tail_kernel<<<BB, 256, 0, stream>>>(hB, mix_w, mix_b, fore_w, fore_b, out);
}

// Round 9
// 110.915 us; speedup vs baseline: 2.3989x; 1.0685x over previous
//
#include <hip/hip_runtime.h>
#include <hip/hip_bf16.h>
#include <math.h>

#define BB 4
#define HH 8
#define PP 32
#define NN 32
#define DD 16
#define LL 1024      // PP*NN
#define WINW 10
#define NFF 6
#define PREDL 96
#define SEQL 512
#define EPSF 1.1920928955078125e-07f
#define KROW 24      // shorts per staged key row (48 B, 16B-aligned)
#define KTS 296      // shorts per VT row (288 keys + 8 pad; 592 B, 16B-aligned)
#define PROW 40      // shorts per P row (80 B, 16B-aligned)
#define XROW 20      // floats per xls row (80 B, 16B-aligned)

typedef __attribute__((ext_vector_type(8))) short bf16x8;
typedef __attribute__((ext_vector_type(4))) float f32x4;

// packed bf16 pair convert (RNE), 1 VALU op for 2 values
__device__ __forceinline__ unsigned cvtpk(float a, float b) {
    unsigned r;
    asm("v_cvt_pk_bf16_f32 %0, %1, %2" : "=v"(r) : "v"(a), "v"(b));
    return r;
}
__device__ __forceinline__ unsigned long long pk64(unsigned lo, unsigned hi) {
    return (unsigned long long)lo | ((unsigned long long)hi << 32);
}

// ======= one layer: signed banded attention + RMSNorm + convFFN + RMSNorm ===
// Round-8 verified math (swapped QK^T, cvt_pk packing, 118.5 us, passed).
// MODE 0: write hout rows (layer 0).
// MODE 1: no hout write; scatter tail contributions into out via
//         fire-and-forget global atomics (tail is linear in hB):
//         out[b,d,fi,n] += mw[h]*fw[fi,p0]*val[n,d]  (+const on h==0,p0==0)
template <int MODE>
__device__ __forceinline__ void layer_body(
    const float* __restrict__ hin, float* __restrict__ hout,
    const float* __restrict__ log_scales, const float* __restrict__ attn_norm,
    const float* __restrict__ up_w, const float* __restrict__ down_w,
    const float* __restrict__ ffn_norm, int layer, int blk, int tid,
    short* hK, short* VT, short (*Pp)[16 * PROW], short (*Pn)[16 * PROW],
    float* xls, float (*comb)[64][8], float (*combl)[2][16],
    const float* __restrict__ mix_w, const float* __restrict__ mix_b,
    const float* __restrict__ fore_w, const float* __restrict__ fore_b,
    float* __restrict__ out)
{
    int bh  = blk >> 5;            // (b*8+h)
    int hh  = bh & 7;
    int p0  = blk & 31;
    int nstage = min(9, (PP - 1) - p0);

    int wid  = tid >> 6;           // wave id
    int qh   = wid >> 1;           // query half (0/1)
    int ch   = wid & 1;            // chunk half (0/1)
    int lane = tid & 63;
    int quad = lane >> 4, n16 = lane & 15;

    // ---- stage keys: fp32 -> bf16 (cvt_pk), row-major + transposed ----
    {
        const float4* src = (const float4*)(hin + ((size_t)bh * LL + (p0 + 1) * NN) * DD);
        int nf4 = nstage * 128;
        #pragma unroll
        for (int k = 0; k < 5; ++k) {
            int i = tid + k * 256;
            if (i < nf4) {
                int row = i >> 2, j = i & 3;
                float4 v = src[i];
                unsigned pk0 = cvtpk(v.x, v.y);
                unsigned pk1 = cvtpk(v.z, v.w);
                *(unsigned long long*)&hK[row * KROW + j * 4] = pk64(pk0, pk1);
                int d0 = j * 4;
                VT[(d0 + 0) * KTS + row] = (short)(pk0 & 0xffff);
                VT[(d0 + 1) * KTS + row] = (short)(pk0 >> 16);
                VT[(d0 + 2) * KTS + row] = (short)(pk1 & 0xffff);
                VT[(d0 + 3) * KTS + row] = (short)(pk1 >> 16);
            }
        }
    }

    // ---- preload Q B-frag and residual (global; overlaps staging) ----
    bf16x8 Aq;
    #pragma unroll
    for (int j = 0; j < 8; ++j) Aq[j] = 0;
    if (quad < 2) {
        const float4* qp4 = (const float4*)(hin +
            ((size_t)bh * LL + p0 * NN + qh * 16 + n16) * DD + quad * 8);
        float4 a = qp4[0], b = qp4[1];
        union { bf16x8 v; unsigned u[4]; } uu;
        uu.u[0] = cvtpk(a.x, a.y);
        uu.u[1] = cvtpk(a.z, a.w);
        uu.u[2] = cvtpk(b.x, b.y);
        uu.u[3] = cvtpk(b.z, b.w);
        Aq = uu.v;
    }
    float rs[4] = {0.f, 0.f, 0.f, 0.f};
    if (ch == 0) {
        #pragma unroll
        for (int r = 0; r < 4; ++r)
            rs[r] = hin[((size_t)bh * LL + p0 * NN + qh * 16 + quad * 4 + r) * DD + n16];
    }

    float sc  = fminf(fmaxf(__expf(log_scales[layer]), 1.0f), 30.0f) * 0.25f;
    float sc2 = sc * 1.4426950408889634f;   // fold log2(e): exp(x) == exp2(sc2*s)

    __syncthreads();   // staging done

    // ---- chunk loop: ch==0 -> chunks [0,4), ch==1 -> chunks [4,nstage) ----
    f32x4 Op, On;
    Op[0] = Op[1] = Op[2] = Op[3] = 0.f;
    On[0] = On[1] = On[2] = On[3] = 0.f;
    float lpp = 0.f, lnn = 0.f;    // per-lane partial for query n16
    short* myPp = Pp[wid];
    short* myPn = Pn[wid];

    int c0 = ch ? 4 : 0;
    int c1 = ch ? nstage : min(4, nstage);

    for (int c = c0; c < c1; ++c) {
        int kb = c * 32;
        #pragma unroll
        for (int kt = 0; kt < 2; ++kt) {
            bf16x8 Bk;   // K fragment (A operand after swap)
            #pragma unroll
            for (int j = 0; j < 8; ++j) Bk[j] = 0;
            if (quad < 2)
                Bk = *(const bf16x8*)&hK[(kb + kt * 16 + n16) * KROW + quad * 8];
            f32x4 z; z[0] = z[1] = z[2] = z[3] = 0.f;
            // SWAPPED: S'[key kt*16+quad*4+r][query n16]
            f32x4 S = __builtin_amdgcn_mfma_f32_16x16x32_bf16(Bk, Aq, z, 0, 0, 0);
            float ep[4], en[4];
            #pragma unroll
            for (int r = 0; r < 4; ++r) {
                float t = sc2 * S[r];
                ep[r] = exp2f(t);
                en[r] = exp2f(-t);
                lpp += ep[r]; lnn += en[r];
            }
            // one b64 write per P-type: P[query n16][keys kt*16+quad*4 .. +3]
            *(unsigned long long*)&myPp[n16 * PROW + kt * 16 + quad * 4] =
                pk64(cvtpk(ep[0], ep[1]), cvtpk(ep[2], ep[3]));
            *(unsigned long long*)&myPn[n16 * PROW + kt * 16 + quad * 4] =
                pk64(cvtpk(en[0], en[1]), cvtpk(en[2], en[3]));
        }
        // PV: contiguous b128 frags (same-wave LDS ordering via lgkmcnt)
        bf16x8 Bv = *(const bf16x8*)&VT[n16 * KTS + kb + quad * 8];
        bf16x8 Ap = *(const bf16x8*)&myPp[n16 * PROW + quad * 8];
        bf16x8 An = *(const bf16x8*)&myPn[n16 * PROW + quad * 8];
        Op = __builtin_amdgcn_mfma_f32_16x16x32_bf16(Ap, Bv, Op, 0, 0, 0);
        On = __builtin_amdgcn_mfma_f32_16x16x32_bf16(An, Bv, On, 0, 0, 0);
    }

    // ---- reduce lp/ln over quads (each lane then has full sum for query n16) ----
    lpp += __shfl_xor(lpp, 16); lpp += __shfl_xor(lpp, 32);
    lnn += __shfl_xor(lnn, 16); lnn += __shfl_xor(lnn, 32);

    // ---- merge ch==1 partials into ch==0 waves ----
    if (ch == 1) {
        *(f32x4*)&comb[qh][lane][0] = Op;
        *(f32x4*)&comb[qh][lane][4] = On;
        if (lane < 16) {
            combl[qh][0][lane] = lpp;
            combl[qh][1][lane] = lnn;
        }
    }
    __syncthreads();
    if (ch == 1) return;   // no barriers past this point

    {
        f32x4 o2 = *(const f32x4*)&comb[qh][lane][0];
        f32x4 n2 = *(const f32x4*)&comb[qh][lane][4];
        #pragma unroll
        for (int r = 0; r < 4; ++r) { Op[r] += o2[r]; On[r] += n2[r]; }
        lpp += combl[qh][0][n16];
        lnn += combl[qh][1][n16];
    }

    // redistribute lp/ln to the O-fragment's row indexing (query quad*4+r)
    float lpr[4], lnr[4];
    #pragma unroll
    for (int r = 0; r < 4; ++r) {
        lpr[r] = __shfl(lpp, quad * 4 + r);
        lnr[r] = __shfl(lnn, quad * 4 + r);
    }

    // ---- residual + attn RMSNorm (C-layout), stash rows to xls ----
    #pragma unroll
    for (int r = 0; r < 4; ++r) {
        float lp = lpr[r], ln = lnr[r];
        float rl = (lp > 0.f) ? (1.0f / lp) : 0.f;
        float rn = (ln > 0.f) ? (1.0f / ln) : 0.f;
        float v  = rs[r] + Op[r] * rl - On[r] * rn;
        float ss = v * v;
        ss += __shfl_xor(ss, 1); ss += __shfl_xor(ss, 2);
        ss += __shfl_xor(ss, 4); ss += __shfl_xor(ss, 8);
        float rr = rsqrtf(ss * (1.0f / 16.0f) + EPSF);
        xls[(qh * 16 + quad * 4 + r) * XROW + n16] = v * rr * attn_norm[layer * DD + n16];
    }
    // this wave wrote all 16 of its xls rows -> same-wave LDS ordering, no barrier

    // ---- conv-FFN + residual + RMSNorm: all 64 lanes (16 q x 4 i-groups) ----
    {
        int q = qh * 16 + n16;       // channel n / row within block
        int g = quad;                // d-group: d = 4g..4g+3

        const float* uw = up_w + (size_t)(layer * 2 * HH + 2 * hh) * 3;
        float w00 = uw[0], w01 = uw[1], w02 = uw[2];
        float w10 = uw[3], w11 = uw[4], w12 = uw[5];
        const float* dw = down_w + (size_t)(layer * HH + hh) * 2;
        float dc0 = dw[0], dc1 = dw[1];

        float xm2 = g ? xls[q * XROW + 4 * g - 2] : 0.f;
        float xm1 = g ? xls[q * XROW + 4 * g - 1] : 0.f;
        float4 xv = *(const float4*)&xls[q * XROW + 4 * g];
        float xa[6] = {xm2, xm1, xv.x, xv.y, xv.z, xv.w};

        float v4[4], ss = 0.f;
        #pragma unroll
        for (int i = 0; i < 4; ++i) {
            float u0 = w00 * xa[i] + w01 * xa[i + 1] + w02 * xa[i + 2];
            float u1 = w10 * xa[i] + w11 * xa[i + 1] + w12 * xa[i + 2];
            float g0 = 0.5f * u0 * (1.0f + erff(u0 * 0.7071067811865475f));
            float g1 = 0.5f * u1 * (1.0f + erff(u1 * 0.7071067811865475f));
            float vv = xa[i] * 0.f + xa[i + 2] + dc0 * g0 + dc1 * g1;
            v4[i] = vv; ss += vv * vv;
        }
        ss += __shfl_xor(ss, 16); ss += __shfl_xor(ss, 32);
        float r2 = rsqrtf(ss * (1.0f / 16.0f) + EPSF);

        const float4 fn = *(const float4*)&ffn_norm[layer * DD + 4 * g];
        float vals[4];
        vals[0] = v4[0] * r2 * fn.x;
        vals[1] = v4[1] * r2 * fn.y;
        vals[2] = v4[2] * r2 * fn.z;
        vals[3] = v4[3] * r2 * fn.w;

        if (MODE == 0) {
            float* op = hout + ((size_t)bh * LL + p0 * NN + q) * DD + 4 * g;
            *(float4*)op = *(float4*)vals;
        } else {
            // tail scatter: out[b, d=4g+i, fi, n=q] += mw[h]*fw[fi,p0]*vals[i]
            // (+ fb[fi] + mb*sum_p fw[fi,p], folded into the h==0,p0==0 blocks)
            int b2 = bh >> 3;
            float mwh = mix_w[hh];
            bool isc = (hh == 0) && (p0 == 0);
            float mbv = mix_b[0];
            #pragma unroll
            for (int fi = 0; fi < NFF; ++fi) {
                float cst = 0.f;
                if (isc) {
                    float s = 0.f;
                    for (int p = 0; p < PP; ++p) s += fore_w[fi * PP + p];
                    cst = fore_b[fi] + mbv * s;
                }
                float c = mwh * fore_w[fi * PP + p0];
                #pragma unroll
                for (int i = 0; i < 4; ++i)
                    atomicAdd(&out[((size_t)(b2 * DD + 4 * g + i) * NFF + fi) * NN + q],
                              c * vals[i] + cst);
            }
        }
    }
}

// ======= dispatch 1: layer 0 + x-passthrough + out-tail zeroing ==============
__global__ __launch_bounds__(256) void layer0_kernel(
    const float* __restrict__ tokens, float* __restrict__ hA,
    const float* __restrict__ log_scales, const float* __restrict__ attn_norm,
    const float* __restrict__ up_w, const float* __restrict__ down_w,
    const float* __restrict__ ffn_norm,
    const float* __restrict__ x_orig, float* __restrict__ out)
{
    __shared__ short hK[9 * 32 * KROW];
    __shared__ short VT[16 * KTS];
    __shared__ short Pp[4][16 * PROW];
    __shared__ short Pn[4][16 * PROW];
    __shared__ float xls[32 * XROW];
    __shared__ float comb[2][64][8];
    __shared__ float combl[2][2][16];

    int blk = blockIdx.x;
    int tid = threadIdx.x;

    // zero the forecast region (12288 floats = 3072 float4; 3 per block)
    if (tid < 3) {
        float4 z; z.x = z.y = z.z = z.w = 0.f;
        ((float4*)out)[blk * 3 + tid] = z;
    }
    // x passthrough: 16 float4 per block
    if (tid < 16) {
        const float4* x4 = (const float4*)x_orig;
        float4* o4 = (float4*)(out + BB * PREDL * NN);
        o4[blk * 16 + tid] = x4[blk * 16 + tid];
    }

    layer_body<0>(tokens, hA, log_scales, attn_norm, up_w, down_w, ffn_norm, 0,
                  blk, tid, hK, VT, Pp, Pn, xls, comb, combl,
                  nullptr, nullptr, nullptr, nullptr, nullptr);
}

// ======= dispatch 2: layer 1 + atomic tail scatter (no hB, no 3rd node) =====
__global__ __launch_bounds__(256) void layer1_kernel(
    const float* __restrict__ hA,
    const float* __restrict__ log_scales, const float* __restrict__ attn_norm,
    const float* __restrict__ up_w, const float* __restrict__ down_w,
    const float* __restrict__ ffn_norm,
    const float* __restrict__ mix_w, const float* __restrict__ mix_b,
    const float* __restrict__ fore_w, const float* __restrict__ fore_b,
    float* __restrict__ out)
{
    __shared__ short hK[9 * 32 * KROW];
    __shared__ short VT[16 * KTS];
    __shared__ short Pp[4][16 * PROW];
    __shared__ short Pn[4][16 * PROW];
    __shared__ float xls[32 * XROW];
    __shared__ float comb[2][64][8];
    __shared__ float combl[2][2][16];

    int blk = blockIdx.x;
    int tid = threadIdx.x;

    layer_body<1>(hA, nullptr, log_scales, attn_norm, up_w, down_w, ffn_norm, 1,
                  blk, tid, hK, VT, Pp, Pn, xls, comb, combl,
                  mix_w, mix_b, fore_w, fore_b, out);
}

// ---------------- host-side input identification by element count ----------------
static int find_by_size(const int* s, int n, int want, int occurrence) {
    int seen = 0;
    for (int i = 0; i < n; ++i)
        if (s[i] == want) { if (seen == occurrence) return i; ++seen; }
    return -1;
}

extern "C" void kernel_launch(void* const* d_in, const int* in_sizes, int n_in,
                              void* d_out, int out_size, void* d_ws, size_t ws_size,
                              hipStream_t stream) {
    int it  = find_by_size(in_sizes, n_in, 524288, 0);
    int ix  = find_by_size(in_sizes, n_in, 65536, 0);
    int ils = find_by_size(in_sizes, n_in, 2, 0);
    int ian = find_by_size(in_sizes, n_in, 32, 0);   // attn_norm_w (1st 32)
    int icu = find_by_size(in_sizes, n_in, 96, 0);
    int icd = find_by_size(in_sizes, n_in, 32, 1);   // conv_down_w (2nd 32)
    int ifn = find_by_size(in_sizes, n_in, 32, 2);   // ffn_norm_w  (3rd 32)
    int imw = find_by_size(in_sizes, n_in, 8, 0);
    int imb = find_by_size(in_sizes, n_in, 1, 0);
    int ifw = find_by_size(in_sizes, n_in, 192, 0);
    int ifb = find_by_size(in_sizes, n_in, 6, 0);
    if (it < 0 || ix < 0 || ils < 0 || ian < 0 || icu < 0 || icd < 0 ||
        ifn < 0 || imw < 0 || imb < 0 || ifw < 0 || ifb < 0) {
        it = 0; ix = 1; ils = 2; ian = 3; icu = 4; icd = 5; ifn = 6;
        imw = 7; imb = 8; ifw = 9; ifb = 10;
    }

    const float* tokens     = (const float*)d_in[it];
    const float* x_orig     = (const float*)d_in[ix];
    const float* log_scales = (const float*)d_in[ils];
    const float* attn_norm  = (const float*)d_in[ian];
    const float* up_w       = (const float*)d_in[icu];
    const float* down_w     = (const float*)d_in[icd];
    const float* ffn_norm   = (const float*)d_in[ifn];
    const float* mix_w      = (const float*)d_in[imw];
    const float* mix_b      = (const float*)d_in[imb];
    const float* fore_w     = (const float*)d_in[ifw];
    const float* fore_b     = (const float*)d_in[ifb];
    float* out = (float*)d_out;

    float* hA = (float*)d_ws;        // [0, 2 MB)

    layer0_kernel<<<1024, 256, 0, stream>>>(tokens, hA, log_scales, attn_norm,
                                            up_w, down_w, ffn_norm, x_orig, out);
    layer1_kernel<<<1024, 256, 0, stream>>>(hA, log_scales, attn_norm,
                                            up_w, down_w, ffn_norm,
                                            mix_w, mix_b, fore_w, fore_b, out);
}